// Round 1
// baseline (4777.589 us; speedup 1.0000x reference)
//
#include <hip/hip_runtime.h>
#include <hip/hip_bf16.h>

// Problem constants: B=16, T=512, E=1024, H=512, 3H=1536, E+H=1536.
//
// Strategy:
//  K1: cast context_emb -> bf16 [8192,1024]
//  K2: cast weights -> bf16 Wx [2*1536,1024], Wh [2*1536,512]
//  K3: input GEMM (MFMA, 128x128 tile): Xg[dir][t][ngate][b] = x @ Wx^T  (bf16 out)
//  K4: recurrence: 16 blocks x 256 thr; 32 waves per direction, each wave owns 16
//      h-columns (i/j/o tiles), Wh fragments persistent in registers (192 VGPR),
//      c-state in registers, h exchanged via global bf16 buffer + per-step
//      device-scope counters.

typedef __attribute__((ext_vector_type(8))) short s8v;
typedef __attribute__((ext_vector_type(4))) short s4v;
typedef __attribute__((ext_vector_type(4))) float f4v;
typedef __attribute__((ext_vector_type(4))) unsigned short us4;

// ws layout (bytes)
#define XBF_OFF   0ull          // 8192*1024*2        = 16,777,216
#define WXBF_OFF  16777216ull   // 3072*1024*2        =  6,291,456
#define WHBF_OFF  23068672ull   // 2*1536*512*2       =  3,145,728
#define XG_OFF    26214400ull   // 2*512*1536*16*2    = 50,331,648
#define HST_OFF   76546048ull   // 2*513*16*512*2     = 16,809,984
#define CNT_OFF   93356032ull   // 2*513*4            =      4,104

static __device__ __forceinline__ short f2bf(float f) {
  __hip_bfloat16 h = __float2bfloat16(f);
  return *reinterpret_cast<short*>(&h);
}
static __device__ __forceinline__ float bf2f(unsigned short u) {
  union { unsigned int i; float f; } x;
  x.i = ((unsigned int)u) << 16;
  return x.f;
}
static __device__ __forceinline__ float sigmoidf_(float x) {
  return 1.0f / (1.0f + __expf(-x));
}
static __device__ __forceinline__ float tanhf_(float x) {
  // stable: x->+inf => 1, x->-inf => -1
  return 1.0f - 2.0f / (1.0f + __expf(2.0f * x));
}

// ---------------- init: h_state[dir][0][b][col] = h0, counters -----------------
__global__ void init_state(const float* __restrict__ h0f, const float* __restrict__ h0b,
                           short* __restrict__ hst, int* __restrict__ cnt) {
  int i = blockIdx.x * 256 + threadIdx.x;
  if (i < 2 * 16 * 512) {
    int dir = i >> 13;
    int r = i & 8191;
    int b = r >> 9;
    int col = r & 511;
    const float* h0 = dir ? h0b : h0f;
    hst[(size_t)dir * 513 * 8192 + b * 512 + col] = f2bf(h0[col]);
  }
  if (i < 2 * 513) {
    cnt[i] = ((i % 513) == 0) ? 32 : 0;  // step-0 state is pre-published
  }
}

// ---------------- cast x to bf16 ----------------
__global__ void cast_x(const float* __restrict__ x, short* __restrict__ xb) {
  int i = (blockIdx.x * 256 + threadIdx.x) * 4;
  f4v v = *reinterpret_cast<const f4v*>(x + i);
  s4v o;
#pragma unroll
  for (int j = 0; j < 4; ++j) o[j] = f2bf(v[j]);
  *reinterpret_cast<s4v*>(xb + i) = o;
}

// ---------------- cast/split weights ----------------
__global__ void cast_w(const float* __restrict__ wf, const float* __restrict__ wb,
                       short* __restrict__ wxb, short* __restrict__ whb) {
  int e = blockIdx.x * 256 + threadIdx.x;  // < 1536*1536
  int dir = blockIdx.y;
  const float* w = dir ? wb : wf;
  int n = e / 1536;
  int k = e - n * 1536;
  short v = f2bf(w[e]);
  if (k < 1024)
    wxb[((size_t)(dir * 1536 + n)) * 1024 + k] = v;
  else
    whb[((size_t)(dir * 1536 + n)) * 512 + (k - 1024)] = v;
}

// ---------------- input GEMM: C = Xb @ Wxb^T, scattered to Xg[dir][t][ng][b] ----
__global__ __launch_bounds__(256) void gemm_in(const short* __restrict__ Xb,
                                               const short* __restrict__ Wxb,
                                               short* __restrict__ Xg) {
  // 128x128 tile, BK=64, LDS rows padded to 72 elems (+16B) -> 2-way-max bank conflicts
  __shared__ short As[128 * 72];
  __shared__ short Bs[128 * 72];
  int tid = threadIdx.x;
  int lane = tid & 63;
  int lr = lane & 15, quad = lane >> 4;
  int widx = tid >> 6;
  int wr = widx >> 1, wc = widx & 1;
  int bm = blockIdx.x, bn = blockIdx.y;

  f4v acc[4][4];
#pragma unroll
  for (int a = 0; a < 4; ++a)
#pragma unroll
    for (int b = 0; b < 4; ++b) acc[a][b] = {0.f, 0.f, 0.f, 0.f};

  const short* Arow = Xb + (size_t)bm * 128 * 1024;
  const short* Brow = Wxb + (size_t)bn * 128 * 1024;

  for (int kt = 0; kt < 16; ++kt) {
#pragma unroll
    for (int c = 0; c < 4; ++c) {
      int fl = c * 2048 + tid * 8;
      int row = fl >> 6, col = fl & 63;
      *reinterpret_cast<s8v*>(&As[row * 72 + col]) =
          *reinterpret_cast<const s8v*>(Arow + row * 1024 + kt * 64 + col);
      *reinterpret_cast<s8v*>(&Bs[row * 72 + col]) =
          *reinterpret_cast<const s8v*>(Brow + row * 1024 + kt * 64 + col);
    }
    __syncthreads();
#pragma unroll
    for (int kk = 0; kk < 2; ++kk) {
      s8v af[4], bfv[4];
#pragma unroll
      for (int mi = 0; mi < 4; ++mi)
        af[mi] = *reinterpret_cast<const s8v*>(&As[(wr * 64 + mi * 16 + lr) * 72 + kk * 32 + quad * 8]);
#pragma unroll
      for (int ni = 0; ni < 4; ++ni)
        bfv[ni] = *reinterpret_cast<const s8v*>(&Bs[(wc * 64 + ni * 16 + lr) * 72 + kk * 32 + quad * 8]);
#pragma unroll
      for (int mi = 0; mi < 4; ++mi)
#pragma unroll
        for (int ni = 0; ni < 4; ++ni)
          acc[mi][ni] = __builtin_amdgcn_mfma_f32_16x16x32_bf16(af[mi], bfv[ni], acc[mi][ni], 0, 0, 0);
    }
    __syncthreads();
  }

  // epilogue: scatter bf16 into Xg[dir][t][ngate][b]
  int ngbase = bn * 128;
  int dir = (ngbase >= 1536) ? 1 : 0;
  int ng0 = ngbase - dir * 1536;
#pragma unroll
  for (int mi = 0; mi < 4; ++mi) {
#pragma unroll
    for (int ni = 0; ni < 4; ++ni) {
      int colg = ng0 + wc * 64 + ni * 16 + lr;
#pragma unroll
      for (int r = 0; r < 4; ++r) {
        int m = bm * 128 + wr * 64 + mi * 16 + quad * 4 + r;  // m = b*512 + t
        int b = m >> 9, t = m & 511;
        Xg[(((size_t)(dir * 512 + t)) * 1536 + colg) * 16 + b] = f2bf(acc[mi][ni][r]);
      }
    }
  }
}

// ---------------- recurrence ----------------
// 16 blocks x 256 threads = 64 waves; wave -> (dir = wg>>5, slice = wg&31).
// Wave owns h-cols [16*slice, 16*slice+16): computes i/j/o gate tiles for them.
__global__ __launch_bounds__(256, 1) void lstm_rec(
    const short* __restrict__ Whb, const short* __restrict__ Xg,
    const float* __restrict__ bfw, const float* __restrict__ bbw,
    const float* __restrict__ c0f, const float* __restrict__ c0b,
    short* __restrict__ hst, int* __restrict__ cnt, float* __restrict__ out) {
  int tid = threadIdx.x;
  int lane = tid & 63, widx = tid >> 6;
  int lr = lane & 15, quad = lane >> 4;
  int wg = blockIdx.x * 4 + widx;
  int dir = wg >> 5;
  int slice = wg & 31;
  int col16 = slice * 16;

  // Persistent B fragments: Wh[n][k], n = g*512 + col16 + lr, lane layout = B[n=lane&15][k=quad*8+j]
  const short* Whd = Whb + (size_t)dir * 1536 * 512;
  s8v Bw[3][16];
#pragma unroll
  for (int g = 0; g < 3; ++g) {
    const short* rp = Whd + (size_t)(g * 512 + col16 + lr) * 512 + quad * 8;
#pragma unroll
    for (int k = 0; k < 16; ++k) Bw[g][k] = *reinterpret_cast<const s8v*>(rp + k * 32);
  }

  const float* bias = dir ? bbw : bfw;
  float bi = bias[col16 + lr];
  float bj = bias[512 + col16 + lr];
  float bo = bias[1024 + col16 + lr];

  const float* c0 = dir ? c0b : c0f;
  float cst[4];
  {
    float c0v = c0[col16 + lr];
#pragma unroll
    for (int r = 0; r < 4; ++r) cst[r] = c0v;
  }

  int* flags = cnt + dir * 513;
  short* hbase = hst + (size_t)dir * 513 * 8192;
  const short* xgbase = Xg + (size_t)dir * 512 * 1536 * 16;

  for (int s = 0; s < 512; ++s) {
    int t = dir ? (511 - s) : s;

    // Prefetch Xg contributions (independent of the flag) to hide latency.
    const short* xgp = xgbase + (size_t)t * 1536 * 16;
    us4 xiv = *reinterpret_cast<const us4*>(xgp + (col16 + lr) * 16 + quad * 4);
    us4 xjv = *reinterpret_cast<const us4*>(xgp + (512 + col16 + lr) * 16 + quad * 4);
    us4 xov = *reinterpret_cast<const us4*>(xgp + (1024 + col16 + lr) * 16 + quad * 4);

    // Wait until all 32 waves of this direction published h(s).
    // Agent-scope acquire load -> L1/L2 invalidate for cross-XCD visibility.
    while (__hip_atomic_load(&flags[s], __ATOMIC_ACQUIRE, __HIP_MEMORY_SCOPE_AGENT) < 32)
      __builtin_amdgcn_s_sleep(1);

    // A fragments: h[m=lane&15][k=quad*8+j], 16B contiguous loads.
    const short* hs = hbase + (size_t)s * 8192 + lr * 512 + quad * 8;
    f4v a0 = {0.f, 0.f, 0.f, 0.f};
    f4v a1 = {0.f, 0.f, 0.f, 0.f};
    f4v a2 = {0.f, 0.f, 0.f, 0.f};
#pragma unroll
    for (int k = 0; k < 16; ++k) {
      s8v av = *reinterpret_cast<const s8v*>(hs + k * 32);
      a0 = __builtin_amdgcn_mfma_f32_16x16x32_bf16(av, Bw[0][k], a0, 0, 0, 0);
      a1 = __builtin_amdgcn_mfma_f32_16x16x32_bf16(av, Bw[1][k], a1, 0, 0, 0);
      a2 = __builtin_amdgcn_mfma_f32_16x16x32_bf16(av, Bw[2][k], a2, 0, 0, 0);
    }

    // Elementwise in C-layout registers: row(batch) = quad*4+r, col = col16+lr
    short* hdst = hbase + (size_t)(s + 1) * 8192;
    float hn[4];
#pragma unroll
    for (int r = 0; r < 4; ++r) {
      float gi = a0[r] + bf2f(xiv[r]) + bi;
      float gj = a1[r] + bf2f(xjv[r]) + bj;
      float go = a2[r] + bf2f(xov[r]) + bo;
      float ii = sigmoidf_(gi);
      float jt = tanhf_(gj);
      float oo = sigmoidf_(go);
      cst[r] = (1.0f - ii) * cst[r] + ii * jt;
      hn[r] = tanhf_(cst[r]) * oo;
      hdst[(quad * 4 + r) * 512 + col16 + lr] = f2bf(hn[r]);
    }

    // Publish h(s+1): drain stores device-wide, then bump the counter.
    __threadfence();
    if (lane == 0)
      __hip_atomic_fetch_add(&flags[s + 1], 1, __ATOMIC_RELAXED, __HIP_MEMORY_SCOPE_AGENT);

    // Output store off the critical path (fp32, [b][t][dir*512+col]).
#pragma unroll
    for (int r = 0; r < 4; ++r)
      out[((size_t)(quad * 4 + r) * 512 + t) * 1024 + dir * 512 + col16 + lr] = hn[r];
  }
}

extern "C" void kernel_launch(void* const* d_in, const int* in_sizes, int n_in,
                              void* d_out, int out_size, void* d_ws, size_t ws_size,
                              hipStream_t stream) {
  const float* x    = (const float*)d_in[0];
  const float* wfw  = (const float*)d_in[1];
  const float* bfw  = (const float*)d_in[2];
  const float* wbw  = (const float*)d_in[3];
  const float* bbw  = (const float*)d_in[4];
  const float* h0f  = (const float*)d_in[5];
  const float* h0b  = (const float*)d_in[6];
  const float* c0f  = (const float*)d_in[7];
  const float* c0b  = (const float*)d_in[8];
  float* out = (float*)d_out;

  unsigned char* ws = (unsigned char*)d_ws;
  short* Xbf  = (short*)(ws + XBF_OFF);
  short* Wxbf = (short*)(ws + WXBF_OFF);
  short* Whbf = (short*)(ws + WHBF_OFF);
  short* Xg   = (short*)(ws + XG_OFF);
  short* hst  = (short*)(ws + HST_OFF);
  int*   cnt  = (int*)(ws + CNT_OFF);

  init_state<<<64, 256, 0, stream>>>(h0f, h0b, hst, cnt);
  cast_x<<<8192, 256, 0, stream>>>(x, Xbf);
  cast_w<<<dim3(9216, 2), 256, 0, stream>>>(wfw, wbw, Wxbf, Whbf);
  gemm_in<<<dim3(64, 24), 256, 0, stream>>>(Xbf, Wxbf, Xg);
  lstm_rec<<<16, 256, 0, stream>>>(Whbf, Xg, bfw, bbw, c0f, c0b, hst, cnt, out);
}

// Round 2
// 3658.750 us; speedup vs baseline: 1.3058x; 1.3058x over previous
//
#include <hip/hip_runtime.h>
#include <hip/hip_bf16.h>

// Problem constants: B=16, T=512, E=1024, H=512, 3H=1536, E+H=1536.
//
// R2 change: lstm_rec sync rebuilt around Infinity-Cache-mediated exchange.
// All h/flag traffic uses sc0sc1 (volatile / relaxed-AGENT) ops -> no L2
// writeback/invalidate instructions anywhere in the step loop (R1's
// __threadfence + ACQUIRE poll emitted buffer_wbl2/buffer_inv per step per
// wave -> 8.5us/step of overhead). 64 blocks x 1 wave: no intra-block sync.

typedef __attribute__((ext_vector_type(8))) short s8v;
typedef __attribute__((ext_vector_type(4))) short s4v;
typedef __attribute__((ext_vector_type(4))) float f4v;
typedef __attribute__((ext_vector_type(4))) unsigned short us4;

// ws layout (bytes)
#define XBF_OFF   0ull          // 8192*1024*2        = 16,777,216
#define WXBF_OFF  16777216ull   // 3072*1024*2        =  6,291,456
#define WHBF_OFF  23068672ull   // 2*1536*512*2       =  3,145,728
#define XG_OFF    26214400ull   // 2*512*1536*16*2    = 50,331,648
#define HST_OFF   76546048ull   // 2*513*16*512*2     = 16,809,984
#define CNT_OFF   93356032ull   // 2*513*4            =      4,104

static __device__ __forceinline__ short f2bf(float f) {
  __hip_bfloat16 h = __float2bfloat16(f);
  return *reinterpret_cast<short*>(&h);
}
static __device__ __forceinline__ float bf2f(unsigned short u) {
  union { unsigned int i; float f; } x;
  x.i = ((unsigned int)u) << 16;
  return x.f;
}
static __device__ __forceinline__ float sigmoidf_(float x) {
  return 1.0f / (1.0f + __expf(-x));
}
static __device__ __forceinline__ float tanhf_(float x) {
  return 1.0f - 2.0f / (1.0f + __expf(2.0f * x));
}

// ---------------- init: h_state[dir][0][b][col] = h0, counters -----------------
__global__ void init_state(const float* __restrict__ h0f, const float* __restrict__ h0b,
                           short* __restrict__ hst, int* __restrict__ cnt) {
  int i = blockIdx.x * 256 + threadIdx.x;
  if (i < 2 * 16 * 512) {
    int dir = i >> 13;
    int r = i & 8191;
    int b = r >> 9;
    int col = r & 511;
    const float* h0 = dir ? h0b : h0f;
    hst[(size_t)dir * 513 * 8192 + b * 512 + col] = f2bf(h0[col]);
  }
  if (i < 2 * 513) {
    cnt[i] = ((i % 513) == 0) ? 32 : 0;  // step-0 state is pre-published
  }
}

// ---------------- cast x to bf16 ----------------
__global__ void cast_x(const float* __restrict__ x, short* __restrict__ xb) {
  int i = (blockIdx.x * 256 + threadIdx.x) * 4;
  f4v v = *reinterpret_cast<const f4v*>(x + i);
  s4v o;
#pragma unroll
  for (int j = 0; j < 4; ++j) o[j] = f2bf(v[j]);
  *reinterpret_cast<s4v*>(xb + i) = o;
}

// ---------------- cast/split weights ----------------
__global__ void cast_w(const float* __restrict__ wf, const float* __restrict__ wb,
                       short* __restrict__ wxb, short* __restrict__ whb) {
  int e = blockIdx.x * 256 + threadIdx.x;  // < 1536*1536
  int dir = blockIdx.y;
  const float* w = dir ? wb : wf;
  int n = e / 1536;
  int k = e - n * 1536;
  short v = f2bf(w[e]);
  if (k < 1024)
    wxb[((size_t)(dir * 1536 + n)) * 1024 + k] = v;
  else
    whb[((size_t)(dir * 1536 + n)) * 512 + (k - 1024)] = v;
}

// ---------------- input GEMM: C = Xb @ Wxb^T, scattered to Xg[dir][t][ng][b] ----
__global__ __launch_bounds__(256) void gemm_in(const short* __restrict__ Xb,
                                               const short* __restrict__ Wxb,
                                               short* __restrict__ Xg) {
  __shared__ short As[128 * 72];
  __shared__ short Bs[128 * 72];
  int tid = threadIdx.x;
  int lane = tid & 63;
  int lr = lane & 15, quad = lane >> 4;
  int widx = tid >> 6;
  int wr = widx >> 1, wc = widx & 1;
  int bm = blockIdx.x, bn = blockIdx.y;

  f4v acc[4][4];
#pragma unroll
  for (int a = 0; a < 4; ++a)
#pragma unroll
    for (int b = 0; b < 4; ++b) acc[a][b] = {0.f, 0.f, 0.f, 0.f};

  const short* Arow = Xb + (size_t)bm * 128 * 1024;
  const short* Brow = Wxb + (size_t)bn * 128 * 1024;

  for (int kt = 0; kt < 16; ++kt) {
#pragma unroll
    for (int c = 0; c < 4; ++c) {
      int fl = c * 2048 + tid * 8;
      int row = fl >> 6, col = fl & 63;
      *reinterpret_cast<s8v*>(&As[row * 72 + col]) =
          *reinterpret_cast<const s8v*>(Arow + row * 1024 + kt * 64 + col);
      *reinterpret_cast<s8v*>(&Bs[row * 72 + col]) =
          *reinterpret_cast<const s8v*>(Brow + row * 1024 + kt * 64 + col);
    }
    __syncthreads();
#pragma unroll
    for (int kk = 0; kk < 2; ++kk) {
      s8v af[4], bfv[4];
#pragma unroll
      for (int mi = 0; mi < 4; ++mi)
        af[mi] = *reinterpret_cast<const s8v*>(&As[(wr * 64 + mi * 16 + lr) * 72 + kk * 32 + quad * 8]);
#pragma unroll
      for (int ni = 0; ni < 4; ++ni)
        bfv[ni] = *reinterpret_cast<const s8v*>(&Bs[(wc * 64 + ni * 16 + lr) * 72 + kk * 32 + quad * 8]);
#pragma unroll
      for (int mi = 0; mi < 4; ++mi)
#pragma unroll
        for (int ni = 0; ni < 4; ++ni)
          acc[mi][ni] = __builtin_amdgcn_mfma_f32_16x16x32_bf16(af[mi], bfv[ni], acc[mi][ni], 0, 0, 0);
    }
    __syncthreads();
  }

  int ngbase = bn * 128;
  int dir = (ngbase >= 1536) ? 1 : 0;
  int ng0 = ngbase - dir * 1536;
#pragma unroll
  for (int mi = 0; mi < 4; ++mi) {
#pragma unroll
    for (int ni = 0; ni < 4; ++ni) {
      int colg = ng0 + wc * 64 + ni * 16 + lr;
#pragma unroll
      for (int r = 0; r < 4; ++r) {
        int m = bm * 128 + wr * 64 + mi * 16 + quad * 4 + r;  // m = b*512 + t
        int b = m >> 9, t = m & 511;
        Xg[(((size_t)(dir * 512 + t)) * 1536 + colg) * 16 + b] = f2bf(acc[mi][ni][r]);
      }
    }
  }
}

// ---------------- recurrence ----------------
// 64 blocks x 64 threads (1 wave each); wave wg=blockIdx: dir=wg>>5, slice=wg&31.
// Wave owns h-cols [16*slice,16*slice+16): i/j/o gate tiles, Wh in 192 VGPRs.
// All cross-wave traffic (h, flags) via sc0sc1 ops served at Infinity Cache;
// no L2 writeback/invalidate in the loop.
__global__ __launch_bounds__(64, 1) void lstm_rec(
    const short* __restrict__ Whb, const short* __restrict__ Xg,
    const float* __restrict__ bfw, const float* __restrict__ bbw,
    const float* __restrict__ c0f, const float* __restrict__ c0b,
    short* __restrict__ hst, int* __restrict__ cnt, float* __restrict__ out) {
  int lane = threadIdx.x & 63;
  int lr = lane & 15, quad = lane >> 4;
  int wg = blockIdx.x;
  int dir = wg >> 5;
  int slice = wg & 31;
  int col16 = slice * 16;

  // Persistent B fragments (normal cached loads; Whb flushed at cast_w kernel end)
  const short* Whd = Whb + (size_t)dir * 1536 * 512;
  s8v Bw[3][16];
#pragma unroll
  for (int g = 0; g < 3; ++g) {
    const short* rp = Whd + (size_t)(g * 512 + col16 + lr) * 512 + quad * 8;
#pragma unroll
    for (int k = 0; k < 16; ++k) Bw[g][k] = *reinterpret_cast<const s8v*>(rp + k * 32);
  }

  const float* bias = dir ? bbw : bfw;
  float bi = bias[col16 + lr];
  float bj = bias[512 + col16 + lr];
  float bo = bias[1024 + col16 + lr];

  const float* c0 = dir ? c0b : c0f;
  float cst[4];
  {
    float c0v = c0[col16 + lr];
#pragma unroll
    for (int r = 0; r < 4; ++r) cst[r] = c0v;
  }

  int* flags = cnt + dir * 513;
  short* hbase = hst + (size_t)dir * 513 * 8192;
  const short* xgbase = Xg + (size_t)dir * 512 * 1536 * 16;

  // First Xg prefetch (t for s=0)
  int t0 = dir ? 511 : 0;
  const short* xgp = xgbase + (size_t)t0 * 1536 * 16;
  us4 xiv = *reinterpret_cast<const us4*>(xgp + (col16 + lr) * 16 + quad * 4);
  us4 xjv = *reinterpret_cast<const us4*>(xgp + (512 + col16 + lr) * 16 + quad * 4);
  us4 xov = *reinterpret_cast<const us4*>(xgp + (1024 + col16 + lr) * 16 + quad * 4);

  for (int s = 0; s < 512; ++s) {
    int t = dir ? (511 - s) : s;

    // Wait until all 32 waves of this direction published h(s).
    // RELAXED agent-scope load: sc0sc1 read at IF, no buffer_inv.
    while (__hip_atomic_load(&flags[s], __ATOMIC_RELAXED, __HIP_MEMORY_SCOPE_AGENT) < 32) {
    }

    // A fragments: h[m=lane&15][k=quad*8+j]; volatile -> sc0sc1 (reads IF).
    const short* hs = hbase + (size_t)s * 8192 + lr * 512 + quad * 8;
    f4v a0 = {0.f, 0.f, 0.f, 0.f};
    f4v a1 = {0.f, 0.f, 0.f, 0.f};
    f4v a2 = {0.f, 0.f, 0.f, 0.f};
#pragma unroll
    for (int k = 0; k < 16; ++k) {
      s8v av = *reinterpret_cast<const volatile s8v*>(hs + k * 32);
      a0 = __builtin_amdgcn_mfma_f32_16x16x32_bf16(av, Bw[0][k], a0, 0, 0, 0);
      a1 = __builtin_amdgcn_mfma_f32_16x16x32_bf16(av, Bw[1][k], a1, 0, 0, 0);
      a2 = __builtin_amdgcn_mfma_f32_16x16x32_bf16(av, Bw[2][k], a2, 0, 0, 0);
    }

    // Elementwise in C-layout regs; volatile h stores (write-through to IF).
    short* hdst = hbase + (size_t)(s + 1) * 8192;
    float hn[4];
#pragma unroll
    for (int r = 0; r < 4; ++r) {
      float gi = a0[r] + bf2f(xiv[r]) + bi;
      float gj = a1[r] + bf2f(xjv[r]) + bj;
      float go = a2[r] + bf2f(xov[r]) + bo;
      float ii = sigmoidf_(gi);
      float jt = tanhf_(gj);
      float oo = sigmoidf_(go);
      cst[r] = (1.0f - ii) * cst[r] + ii * jt;
      hn[r] = tanhf_(cst[r]) * oo;
      *(volatile short*)(hdst + (quad * 4 + r) * 512 + col16 + lr) = f2bf(hn[r]);
    }

    // Release: drain the 4 h stores to IF, then fire-and-forget flag bump
    // (result unused -> no-return atomic, no wait on its completion).
    asm volatile("s_waitcnt vmcnt(0)" ::: "memory");
    if (lane == 0)
      __hip_atomic_fetch_add(&flags[s + 1], 1, __ATOMIC_RELAXED, __HIP_MEMORY_SCOPE_AGENT);

    // Off-critical-path work: output store + next-step Xg prefetch.
#pragma unroll
    for (int r = 0; r < 4; ++r)
      out[((size_t)(quad * 4 + r) * 512 + t) * 1024 + dir * 512 + col16 + lr] = hn[r];

    int tn = dir ? (511 - (s + 1)) : (s + 1);
    if (s < 511) {
      const short* xgn = xgbase + (size_t)tn * 1536 * 16;
      xiv = *reinterpret_cast<const us4*>(xgn + (col16 + lr) * 16 + quad * 4);
      xjv = *reinterpret_cast<const us4*>(xgn + (512 + col16 + lr) * 16 + quad * 4);
      xov = *reinterpret_cast<const us4*>(xgn + (1024 + col16 + lr) * 16 + quad * 4);
    }
  }
}

extern "C" void kernel_launch(void* const* d_in, const int* in_sizes, int n_in,
                              void* d_out, int out_size, void* d_ws, size_t ws_size,
                              hipStream_t stream) {
  const float* x    = (const float*)d_in[0];
  const float* wfw  = (const float*)d_in[1];
  const float* bfw  = (const float*)d_in[2];
  const float* wbw  = (const float*)d_in[3];
  const float* bbw  = (const float*)d_in[4];
  const float* h0f  = (const float*)d_in[5];
  const float* h0b  = (const float*)d_in[6];
  const float* c0f  = (const float*)d_in[7];
  const float* c0b  = (const float*)d_in[8];
  float* out = (float*)d_out;

  unsigned char* ws = (unsigned char*)d_ws;
  short* Xbf  = (short*)(ws + XBF_OFF);
  short* Wxbf = (short*)(ws + WXBF_OFF);
  short* Whbf = (short*)(ws + WHBF_OFF);
  short* Xg   = (short*)(ws + XG_OFF);
  short* hst  = (short*)(ws + HST_OFF);
  int*   cnt  = (int*)(ws + CNT_OFF);

  init_state<<<64, 256, 0, stream>>>(h0f, h0b, hst, cnt);
  cast_x<<<8192, 256, 0, stream>>>(x, Xbf);
  cast_w<<<dim3(9216, 2), 256, 0, stream>>>(wfw, wbw, Wxbf, Whbf);
  gemm_in<<<dim3(64, 24), 256, 0, stream>>>(Xbf, Wxbf, Xg);
  lstm_rec<<<64, 64, 0, stream>>>(Whbf, Xg, bfw, bbw, c0f, c0b, hst, cnt, out);
}

// Round 3
// 2767.861 us; speedup vs baseline: 1.7261x; 1.3219x over previous
//
#include <hip/hip_runtime.h>
#include <hip/hip_bf16.h>

// Problem constants: B=16, T=512, E=1024, H=512, 3H=1536, E+H=1536.
//
// R3 change: R2's volatile h exchange serialized (LLVM drains vmcnt between
// consecutive volatile ops -> 15+ IF round-trips/step = 16k cyc). Replace:
//   consumer h loads: 32x __hip_atomic_load(u64, RELAXED, AGENT) - pipelined,
//                     one ~900cyc IF latency for the whole fragment set;
//   producer h stores: inline-asm global_store_short sc0 sc1 (no result
//                     hazard), single s_waitcnt vmcnt(0) release, then
//                     fire-and-forget agent atomic flag add.

typedef __attribute__((ext_vector_type(8))) short s8v;
typedef __attribute__((ext_vector_type(4))) short s4v;
typedef __attribute__((ext_vector_type(4))) float f4v;
typedef __attribute__((ext_vector_type(4))) unsigned short us4;
typedef unsigned long long u64;

// ws layout (bytes)
#define XBF_OFF   0ull          // 8192*1024*2        = 16,777,216
#define WXBF_OFF  16777216ull   // 3072*1024*2        =  6,291,456
#define WHBF_OFF  23068672ull   // 2*1536*512*2       =  3,145,728
#define XG_OFF    26214400ull   // 2*512*1536*16*2    = 50,331,648
#define HST_OFF   76546048ull   // 2*513*16*512*2     = 16,809,984
#define CNT_OFF   93356032ull   // 2*513*4            =      4,104

static __device__ __forceinline__ short f2bf(float f) {
  __hip_bfloat16 h = __float2bfloat16(f);
  return *reinterpret_cast<short*>(&h);
}
static __device__ __forceinline__ float bf2f(unsigned short u) {
  union { unsigned int i; float f; } x;
  x.i = ((unsigned int)u) << 16;
  return x.f;
}
static __device__ __forceinline__ float sigmoidf_(float x) {
  return 1.0f / (1.0f + __expf(-x));
}
static __device__ __forceinline__ float tanhf_(float x) {
  return 1.0f - 2.0f / (1.0f + __expf(2.0f * x));
}

// ---------------- init: h_state[dir][0][b][col] = h0, counters -----------------
__global__ void init_state(const float* __restrict__ h0f, const float* __restrict__ h0b,
                           short* __restrict__ hst, int* __restrict__ cnt) {
  int i = blockIdx.x * 256 + threadIdx.x;
  if (i < 2 * 16 * 512) {
    int dir = i >> 13;
    int r = i & 8191;
    int b = r >> 9;
    int col = r & 511;
    const float* h0 = dir ? h0b : h0f;
    hst[(size_t)dir * 513 * 8192 + b * 512 + col] = f2bf(h0[col]);
  }
  if (i < 2 * 513) {
    cnt[i] = ((i % 513) == 0) ? 32 : 0;  // step-0 state is pre-published
  }
}

// ---------------- cast x to bf16 ----------------
__global__ void cast_x(const float* __restrict__ x, short* __restrict__ xb) {
  int i = (blockIdx.x * 256 + threadIdx.x) * 4;
  f4v v = *reinterpret_cast<const f4v*>(x + i);
  s4v o;
#pragma unroll
  for (int j = 0; j < 4; ++j) o[j] = f2bf(v[j]);
  *reinterpret_cast<s4v*>(xb + i) = o;
}

// ---------------- cast/split weights ----------------
__global__ void cast_w(const float* __restrict__ wf, const float* __restrict__ wb,
                       short* __restrict__ wxb, short* __restrict__ whb) {
  int e = blockIdx.x * 256 + threadIdx.x;  // < 1536*1536
  int dir = blockIdx.y;
  const float* w = dir ? wb : wf;
  int n = e / 1536;
  int k = e - n * 1536;
  short v = f2bf(w[e]);
  if (k < 1024)
    wxb[((size_t)(dir * 1536 + n)) * 1024 + k] = v;
  else
    whb[((size_t)(dir * 1536 + n)) * 512 + (k - 1024)] = v;
}

// ---------------- input GEMM: C = Xb @ Wxb^T, scattered to Xg[dir][t][ng][b] ----
__global__ __launch_bounds__(256) void gemm_in(const short* __restrict__ Xb,
                                               const short* __restrict__ Wxb,
                                               short* __restrict__ Xg) {
  __shared__ short As[128 * 72];
  __shared__ short Bs[128 * 72];
  int tid = threadIdx.x;
  int lane = tid & 63;
  int lr = lane & 15, quad = lane >> 4;
  int widx = tid >> 6;
  int wr = widx >> 1, wc = widx & 1;
  int bm = blockIdx.x, bn = blockIdx.y;

  f4v acc[4][4];
#pragma unroll
  for (int a = 0; a < 4; ++a)
#pragma unroll
    for (int b = 0; b < 4; ++b) acc[a][b] = {0.f, 0.f, 0.f, 0.f};

  const short* Arow = Xb + (size_t)bm * 128 * 1024;
  const short* Brow = Wxb + (size_t)bn * 128 * 1024;

  for (int kt = 0; kt < 16; ++kt) {
#pragma unroll
    for (int c = 0; c < 4; ++c) {
      int fl = c * 2048 + tid * 8;
      int row = fl >> 6, col = fl & 63;
      *reinterpret_cast<s8v*>(&As[row * 72 + col]) =
          *reinterpret_cast<const s8v*>(Arow + row * 1024 + kt * 64 + col);
      *reinterpret_cast<s8v*>(&Bs[row * 72 + col]) =
          *reinterpret_cast<const s8v*>(Brow + row * 1024 + kt * 64 + col);
    }
    __syncthreads();
#pragma unroll
    for (int kk = 0; kk < 2; ++kk) {
      s8v af[4], bfv[4];
#pragma unroll
      for (int mi = 0; mi < 4; ++mi)
        af[mi] = *reinterpret_cast<const s8v*>(&As[(wr * 64 + mi * 16 + lr) * 72 + kk * 32 + quad * 8]);
#pragma unroll
      for (int ni = 0; ni < 4; ++ni)
        bfv[ni] = *reinterpret_cast<const s8v*>(&Bs[(wc * 64 + ni * 16 + lr) * 72 + kk * 32 + quad * 8]);
#pragma unroll
      for (int mi = 0; mi < 4; ++mi)
#pragma unroll
        for (int ni = 0; ni < 4; ++ni)
          acc[mi][ni] = __builtin_amdgcn_mfma_f32_16x16x32_bf16(af[mi], bfv[ni], acc[mi][ni], 0, 0, 0);
    }
    __syncthreads();
  }

  int ngbase = bn * 128;
  int dir = (ngbase >= 1536) ? 1 : 0;
  int ng0 = ngbase - dir * 1536;
#pragma unroll
  for (int mi = 0; mi < 4; ++mi) {
#pragma unroll
    for (int ni = 0; ni < 4; ++ni) {
      int colg = ng0 + wc * 64 + ni * 16 + lr;
#pragma unroll
      for (int r = 0; r < 4; ++r) {
        int m = bm * 128 + wr * 64 + mi * 16 + quad * 4 + r;  // m = b*512 + t
        int b = m >> 9, t = m & 511;
        Xg[(((size_t)(dir * 512 + t)) * 1536 + colg) * 16 + b] = f2bf(acc[mi][ni][r]);
      }
    }
  }
}

// ---------------- recurrence ----------------
// 64 blocks x 64 threads (1 wave each); wave wg=blockIdx: dir=wg>>5, slice=wg&31.
// Wave owns h-cols [16*slice,16*slice+16): i/j/o gate tiles, Wh in 192 VGPRs.
// All cross-wave traffic via agent-scope (sc0 sc1) ops served at the Infinity
// Cache; pipelined (atomic u64 loads, asm short stores) — no volatile, no
// per-op serializing waits, no L2 wb/inv in the loop.
__global__ __launch_bounds__(64, 1) void lstm_rec(
    const short* __restrict__ Whb, const short* __restrict__ Xg,
    const float* __restrict__ bfw, const float* __restrict__ bbw,
    const float* __restrict__ c0f, const float* __restrict__ c0b,
    short* __restrict__ hst, int* __restrict__ cnt, float* __restrict__ out) {
  int lane = threadIdx.x & 63;
  int lr = lane & 15, quad = lane >> 4;
  int wg = blockIdx.x;
  int dir = wg >> 5;
  int slice = wg & 31;
  int col16 = slice * 16;

  // Persistent B fragments (normal cached loads)
  const short* Whd = Whb + (size_t)dir * 1536 * 512;
  s8v Bw[3][16];
#pragma unroll
  for (int g = 0; g < 3; ++g) {
    const short* rp = Whd + (size_t)(g * 512 + col16 + lr) * 512 + quad * 8;
#pragma unroll
    for (int k = 0; k < 16; ++k) Bw[g][k] = *reinterpret_cast<const s8v*>(rp + k * 32);
  }

  const float* bias = dir ? bbw : bfw;
  float bi = bias[col16 + lr];
  float bj = bias[512 + col16 + lr];
  float bo = bias[1024 + col16 + lr];

  const float* c0 = dir ? c0b : c0f;
  float cst[4];
  {
    float c0v = c0[col16 + lr];
#pragma unroll
    for (int r = 0; r < 4; ++r) cst[r] = c0v;
  }

  int* flags = cnt + dir * 513;
  short* hbase = hst + (size_t)dir * 513 * 8192;
  const short* xgbase = Xg + (size_t)dir * 512 * 1536 * 16;

  // Per-lane u64 index into an h step-frame: row lr, cols quad*8 + k*32
  // byte offset = lr*1024 + quad*16 + k*64  -> u64 idx = lr*128 + quad*2 + k*8
  int hqidx = lr * 128 + quad * 2;

  // First Xg prefetch (t for s=0)
  int t0 = dir ? 511 : 0;
  const short* xgp = xgbase + (size_t)t0 * 1536 * 16;
  us4 xiv = *reinterpret_cast<const us4*>(xgp + (col16 + lr) * 16 + quad * 4);
  us4 xjv = *reinterpret_cast<const us4*>(xgp + (512 + col16 + lr) * 16 + quad * 4);
  us4 xov = *reinterpret_cast<const us4*>(xgp + (1024 + col16 + lr) * 16 + quad * 4);

  for (int s = 0; s < 512; ++s) {
    int t = dir ? (511 - s) : s;

    // Wait until all 32 waves of this direction published h(s).
    while (__hip_atomic_load(&flags[s], __ATOMIC_RELAXED, __HIP_MEMORY_SCOPE_AGENT) < 32) {
    }

    // A fragments via pipelined agent-scope u64 loads (all 32 in flight).
    const u64* hq = reinterpret_cast<const u64*>(hbase + (size_t)s * 8192);
    u64 qa[16][2];
#pragma unroll
    for (int k = 0; k < 16; ++k) {
      qa[k][0] = __hip_atomic_load(hq + hqidx + k * 8, __ATOMIC_RELAXED, __HIP_MEMORY_SCOPE_AGENT);
      qa[k][1] = __hip_atomic_load(hq + hqidx + k * 8 + 1, __ATOMIC_RELAXED, __HIP_MEMORY_SCOPE_AGENT);
    }

    f4v a0 = {0.f, 0.f, 0.f, 0.f};
    f4v a1 = {0.f, 0.f, 0.f, 0.f};
    f4v a2 = {0.f, 0.f, 0.f, 0.f};
#pragma unroll
    for (int k = 0; k < 16; ++k) {
      union { u64 q[2]; s8v v; } u;
      u.q[0] = qa[k][0];
      u.q[1] = qa[k][1];
      a0 = __builtin_amdgcn_mfma_f32_16x16x32_bf16(u.v, Bw[0][k], a0, 0, 0, 0);
      a1 = __builtin_amdgcn_mfma_f32_16x16x32_bf16(u.v, Bw[1][k], a1, 0, 0, 0);
      a2 = __builtin_amdgcn_mfma_f32_16x16x32_bf16(u.v, Bw[2][k], a2, 0, 0, 0);
    }

    // Elementwise in C-layout regs; h stores via asm (sc0 sc1, write-through
    // to IF, pipelined, no compiler serialization).
    short* hdst = hbase + (size_t)(s + 1) * 8192;
    float hn[4];
#pragma unroll
    for (int r = 0; r < 4; ++r) {
      float gi = a0[r] + bf2f(xiv[r]) + bi;
      float gj = a1[r] + bf2f(xjv[r]) + bj;
      float go = a2[r] + bf2f(xov[r]) + bo;
      float ii = sigmoidf_(gi);
      float jt = tanhf_(gj);
      float oo = sigmoidf_(go);
      cst[r] = (1.0f - ii) * cst[r] + ii * jt;
      hn[r] = tanhf_(cst[r]) * oo;
      short hv = f2bf(hn[r]);
      const short* hp = hdst + (quad * 4 + r) * 512 + col16 + lr;
      asm volatile("global_store_short %0, %1, off sc0 sc1"
                   :: "v"(hp), "v"((int)hv) : "memory");
    }

    // Release: drain the 4 h stores to IF, then fire-and-forget flag bump.
    asm volatile("s_waitcnt vmcnt(0)" ::: "memory");
    if (lane == 0)
      (void)__hip_atomic_fetch_add(&flags[s + 1], 1, __ATOMIC_RELAXED, __HIP_MEMORY_SCOPE_AGENT);

    // Off-critical-path: output store + next-step Xg prefetch.
#pragma unroll
    for (int r = 0; r < 4; ++r)
      out[((size_t)(quad * 4 + r) * 512 + t) * 1024 + dir * 512 + col16 + lr] = hn[r];

    if (s < 511) {
      int tn = dir ? (511 - (s + 1)) : (s + 1);
      const short* xgn = xgbase + (size_t)tn * 1536 * 16;
      xiv = *reinterpret_cast<const us4*>(xgn + (col16 + lr) * 16 + quad * 4);
      xjv = *reinterpret_cast<const us4*>(xgn + (512 + col16 + lr) * 16 + quad * 4);
      xov = *reinterpret_cast<const us4*>(xgn + (1024 + col16 + lr) * 16 + quad * 4);
    }
  }
}

extern "C" void kernel_launch(void* const* d_in, const int* in_sizes, int n_in,
                              void* d_out, int out_size, void* d_ws, size_t ws_size,
                              hipStream_t stream) {
  const float* x    = (const float*)d_in[0];
  const float* wfw  = (const float*)d_in[1];
  const float* bfw  = (const float*)d_in[2];
  const float* wbw  = (const float*)d_in[3];
  const float* bbw  = (const float*)d_in[4];
  const float* h0f  = (const float*)d_in[5];
  const float* h0b  = (const float*)d_in[6];
  const float* c0f  = (const float*)d_in[7];
  const float* c0b  = (const float*)d_in[8];
  float* out = (float*)d_out;

  unsigned char* ws = (unsigned char*)d_ws;
  short* Xbf  = (short*)(ws + XBF_OFF);
  short* Wxbf = (short*)(ws + WXBF_OFF);
  short* Whbf = (short*)(ws + WHBF_OFF);
  short* Xg   = (short*)(ws + XG_OFF);
  short* hst  = (short*)(ws + HST_OFF);
  int*   cnt  = (int*)(ws + CNT_OFF);

  init_state<<<64, 256, 0, stream>>>(h0f, h0b, hst, cnt);
  cast_x<<<8192, 256, 0, stream>>>(x, Xbf);
  cast_w<<<dim3(9216, 2), 256, 0, stream>>>(wfw, wbw, Wxbf, Whbf);
  gemm_in<<<dim3(64, 24), 256, 0, stream>>>(Xbf, Wxbf, Xg);
  lstm_rec<<<64, 64, 0, stream>>>(Whbf, Xg, bfw, bbw, c0f, c0b, hst, cnt, out);
}